// Round 5
// baseline (658.896 us; speedup 1.0000x reference)
//
#include <hip/hip_runtime.h>

typedef unsigned short u16;
typedef __attribute__((ext_vector_type(8))) short bf16x8;
typedef __attribute__((ext_vector_type(4))) float f32x4;

__device__ __forceinline__ float bf2f(u16 u) { return __uint_as_float(((unsigned)u) << 16); }
__device__ __forceinline__ u16 f2bf(float f) {
  unsigned u = __float_as_uint(f);
  u += 0x7fffu + ((u >> 16) & 1u);   // RNE
  return (u16)(u >> 16);
}
__device__ __forceinline__ void bf2x2(unsigned w, float& lo, float& hi) {
  lo = __uint_as_float(w << 16);
  hi = __uint_as_float(w & 0xffff0000u);
}

// ---------------------------------------------------------------------------
// Split x (f32) -> hi/lo bf16
// ---------------------------------------------------------------------------
__global__ __launch_bounds__(256) void splitx_kernel(
    const float* __restrict__ x, u16* __restrict__ XH, u16* __restrict__ XL, int n)
{
  int i = blockIdx.x * 256 + threadIdx.x;
  if (i >= n) return;
  float v = x[i];
  u16 h = f2bf(v);
  XH[i] = h;
  XL[i] = f2bf(v - bf2f(h));
}

// ---------------------------------------------------------------------------
// Transpose+split the 5 weight matrices: WT[n*K+k] = split(W[k*N+n]).
// Regions (flat output index): Wl1[0,65536) K=128,N=512; Wr1[+65536);
// Wl2[131072,262144) K=512,N=256; Wr2[+131072); Wjk[393216,507904) K=896,N=128.
// ---------------------------------------------------------------------------
__global__ __launch_bounds__(256) void wsplit_kernel(
    const float* __restrict__ w0, const float* __restrict__ w1,
    const float* __restrict__ w2, const float* __restrict__ w3,
    const float* __restrict__ w4,
    u16* __restrict__ WTH, u16* __restrict__ WTL)
{
  int i = blockIdx.x * 256 + threadIdx.x;
  if (i >= 507904) return;
  const float* src; int j = i, K, N;
  if (j < 65536)       { src = w0; K = 128; N = 512; }
  else if (j < 131072) { src = w1; K = 128; N = 512; j -= 65536; }
  else if (j < 262144) { src = w2; K = 512; N = 256; j -= 131072; }
  else if (j < 393216) { src = w3; K = 512; N = 256; j -= 262144; }
  else                 { src = w4; K = 896; N = 128; j -= 393216; }
  int n = j / K, k = j - n * K;
  float v = src[(size_t)k * N + n];
  u16 h = f2bf(v);
  WTH[i] = h;
  WTL[i] = f2bf(v - bf2f(h));
}

// ---------------------------------------------------------------------------
// CSR build: histogram -> exclusive scan -> scatter srcs by dst
// ---------------------------------------------------------------------------
__global__ __launch_bounds__(256) void hist_kernel(
    const int* __restrict__ ei, int E, int ET, int* __restrict__ cnt)
{
  int e = blockIdx.x * 256 + threadIdx.x;
  if (e >= ET) return;
  int d = (e < E) ? ei[E + e] : (e - E);
  atomicAdd(&cnt[d], 1);
}

__global__ __launch_bounds__(1024) void scan_kernel(
    const int* __restrict__ cnt, int* __restrict__ rowptr, int n)
{
  __shared__ int buf[1024];
  __shared__ int carry;
  if (threadIdx.x == 0) carry = 0;
  __syncthreads();
  for (int base = 0; base < n; base += 1024) {
    int i = base + threadIdx.x;
    int v = (i < n) ? cnt[i] : 0;
    buf[threadIdx.x] = v;
    __syncthreads();
    for (int ofs = 1; ofs < 1024; ofs <<= 1) {
      int t = (threadIdx.x >= ofs) ? buf[threadIdx.x - ofs] : 0;
      __syncthreads();
      buf[threadIdx.x] += t;
      __syncthreads();
    }
    int incl = buf[threadIdx.x];
    int c = carry;
    if (i < n) rowptr[i] = c + incl - v;
    int total = buf[1023];
    __syncthreads();
    if (threadIdx.x == 0) carry = c + total;
    __syncthreads();
  }
  if (threadIdx.x == 0) rowptr[n] = carry;
}

__global__ __launch_bounds__(256) void scatter_kernel(
    const int* __restrict__ ei, int E, int ET,
    const int* __restrict__ rowptr, int* __restrict__ cur, int* __restrict__ srcs)
{
  int e = blockIdx.x * 256 + threadIdx.x;
  if (e >= ET) return;
  int s, d;
  if (e < E) { s = ei[e]; d = ei[E + e]; } else { s = e - E; d = s; }
  int pos = rowptr[d] + atomicAdd(&cur[d], 1);
  srcs[pos] = s;
}

// ---------------------------------------------------------------------------
// GEMM v2 (no LDS): C[M, coff:coff+Nc] = sum_s A_s[M,K_s] @ B_s + bias.
// B given TRANSPOSED (BT[n][k], row stride ldbt). Block = 128 rows x 64 cols,
// 4 waves, each wave 32 rows x 64 cols: per 32-k step 2 A-frag + 4 B-frag
// global 16B loads + 8 mfma_16x16x32_bf16. No barriers.
// ---------------------------------------------------------------------------
template<bool BF16OUT>
__global__ __launch_bounds__(256) void gemm3t_kernel(
    const u16* __restrict__ A0, int lda0, int K0,
    const u16* __restrict__ A1, int lda1, int K1,
    const u16* __restrict__ A2, int lda2, int K2,
    const u16* __restrict__ BT0, const u16* __restrict__ BT1, const u16* __restrict__ BT2,
    int ldbt,
    const float* __restrict__ bias,
    void* __restrict__ Cv, int ldc, int coff,
    int M)
{
  const int tid  = threadIdx.x;
  const int lane = tid & 63;
  const int wid  = tid >> 6;
  const int quad = lane >> 4;
  const int r16  = lane & 15;
  const int m0   = blockIdx.x * 128;
  const int n0   = blockIdx.y * 64;

  f32x4 acc[2][4] = {{{0,0,0,0},{0,0,0,0},{0,0,0,0},{0,0,0,0}},
                     {{0,0,0,0},{0,0,0,0},{0,0,0,0},{0,0,0,0}}};

  const u16* As[3]  = {A0, A1, A2};
  const u16* BTs[3] = {BT0, BT1, BT2};
  const int  Ks[3]  = {K0, K1, K2};
  const int  lds_[3] = {lda0, lda1, lda2};

#pragma unroll
  for (int s = 0; s < 3; ++s) {
    const int K = Ks[s];
    if (K == 0) continue;
    const u16* A  = As[s];
    const u16* BT = BTs[s];
    const int lda = lds_[s];
    int ar0 = m0 + wid * 32 + r16;      if (ar0 >= M) ar0 = M - 1;
    int ar1 = m0 + wid * 32 + 16 + r16; if (ar1 >= M) ar1 = M - 1;
    const u16* ap0 = A + (size_t)ar0 * lda + quad * 8;
    const u16* ap1 = A + (size_t)ar1 * lda + quad * 8;
    const u16* bp  = BT + (size_t)(n0 + r16) * ldbt + quad * 8;

#pragma unroll 2
    for (int k0 = 0; k0 < K; k0 += 32) {
      bf16x8 a0 = *reinterpret_cast<const bf16x8*>(ap0 + k0);
      bf16x8 a1 = *reinterpret_cast<const bf16x8*>(ap1 + k0);
      bf16x8 b0 = *reinterpret_cast<const bf16x8*>(bp + k0);
      bf16x8 b1 = *reinterpret_cast<const bf16x8*>(bp + (size_t)16 * ldbt + k0);
      bf16x8 b2 = *reinterpret_cast<const bf16x8*>(bp + (size_t)32 * ldbt + k0);
      bf16x8 b3 = *reinterpret_cast<const bf16x8*>(bp + (size_t)48 * ldbt + k0);
      acc[0][0] = __builtin_amdgcn_mfma_f32_16x16x32_bf16(a0, b0, acc[0][0], 0, 0, 0);
      acc[1][0] = __builtin_amdgcn_mfma_f32_16x16x32_bf16(a1, b0, acc[1][0], 0, 0, 0);
      acc[0][1] = __builtin_amdgcn_mfma_f32_16x16x32_bf16(a0, b1, acc[0][1], 0, 0, 0);
      acc[1][1] = __builtin_amdgcn_mfma_f32_16x16x32_bf16(a1, b1, acc[1][1], 0, 0, 0);
      acc[0][2] = __builtin_amdgcn_mfma_f32_16x16x32_bf16(a0, b2, acc[0][2], 0, 0, 0);
      acc[1][2] = __builtin_amdgcn_mfma_f32_16x16x32_bf16(a1, b2, acc[1][2], 0, 0, 0);
      acc[0][3] = __builtin_amdgcn_mfma_f32_16x16x32_bf16(a0, b3, acc[0][3], 0, 0, 0);
      acc[1][3] = __builtin_amdgcn_mfma_f32_16x16x32_bf16(a1, b3, acc[1][3], 0, 0, 0);
    }
  }

#pragma unroll
  for (int nc = 0; nc < 4; ++nc) {
    const int col = n0 + nc * 16 + r16;
    const float bv = bias ? bias[col] : 0.f;
#pragma unroll
    for (int half = 0; half < 2; ++half) {
#pragma unroll
      for (int r = 0; r < 4; ++r) {
        int m = m0 + wid * 32 + half * 16 + quad * 4 + r;
        if (m < M) {
          float v = acc[half][nc][r] + bv;
          if (BF16OUT) ((u16*)Cv)[(size_t)m * ldc + coff + col] = f2bf(v);
          else         ((float*)Cv)[(size_t)m * ldc + coff + col] = v;
        }
      }
    }
  }
}

// ---------------------------------------------------------------------------
// Fused GATv2 aggregation (bf16 XLR): one wave per dst node, online softmax
// per head, register accumulation. XLR row (u16): [xl(0..D-1) | xr(D..2D-1)].
// ---------------------------------------------------------------------------
template<int VPL>
__device__ __forceinline__ void load_row(const u16* p, float* dst) {
  if constexpr (VPL == 8) {
    uint4 t = *reinterpret_cast<const uint4*>(p);
    bf2x2(t.x, dst[0], dst[1]); bf2x2(t.y, dst[2], dst[3]);
    bf2x2(t.z, dst[4], dst[5]); bf2x2(t.w, dst[6], dst[7]);
  } else {
    uint2 t = *reinterpret_cast<const uint2*>(p);
    bf2x2(t.x, dst[0], dst[1]); bf2x2(t.y, dst[2], dst[3]);
  }
}

template<int C, bool WLO>
__global__ __launch_bounds__(256) void gat_node_kernel(
    const u16* __restrict__ XLR,
    const int* __restrict__ rowptr, const int* __restrict__ srcs,
    const float* __restrict__ att, const float* __restrict__ bias,
    u16* __restrict__ Hh, u16* __restrict__ Hl, int Nn)
{
  constexpr int D = C * 8;
  constexpr int VPL = D / 64;          // 8 (C=64) or 4 (C=32)
  const int lane = threadIdx.x & 63;
  const int wv  = (blockIdx.x * 256 + threadIdx.x) >> 6;
  const int nwv = (gridDim.x * 256) >> 6;

  float attR[VPL], biasR[VPL];
#pragma unroll
  for (int w = 0; w < VPL; ++w) {
    attR[w]  = att[lane * VPL + w];
    biasR[w] = bias[lane * VPL + w];
  }

  for (int d = wv; d < Nn; d += nwv) {
    float xrR[VPL];
    load_row<VPL>(XLR + (size_t)d * (2 * D) + D + lane * VPL, xrR);

    const int jb = rowptr[d], je = rowptr[d + 1];
    float m = -INFINITY, den = 0.f;
    float acc[VPL];
#pragma unroll
    for (int w = 0; w < VPL; ++w) acc[w] = 0.f;

    float xlR[VPL];
    load_row<VPL>(XLR + (size_t)srcs[jb] * (2 * D) + lane * VPL, xlR);

    for (int j = jb; j < je; ++j) {
      float xlN[VPL];
      if (j + 1 < je)
        load_row<VPL>(XLR + (size_t)srcs[j + 1] * (2 * D) + lane * VPL, xlN);
      float p = 0.f;
#pragma unroll
      for (int w = 0; w < VPL; ++w) {
        float v = xlR[w] + xrR[w];
        v = v > 0.f ? v : 0.2f * v;
        p += v * attR[w];
      }
      p += __shfl_xor(p, 1);
      p += __shfl_xor(p, 2);
      p += __shfl_xor(p, 4);              // logit for this lane's head
      const float mn = fmaxf(m, p);
      const float f  = __expf(m - mn);    // m=-inf first iter -> f=0
      const float pe = __expf(p - mn);
      den = den * f + pe;
#pragma unroll
      for (int w = 0; w < VPL; ++w) acc[w] = acc[w] * f + pe * xlR[w];
      m = mn;
      if (j + 1 < je) {
#pragma unroll
        for (int w = 0; w < VPL; ++w) xlR[w] = xlN[w];
      }
    }

    const float inv = 1.f / den;
    u16* hh = Hh + (size_t)d * D + lane * VPL;
    u16* hl = WLO ? (Hl + (size_t)d * D + lane * VPL) : nullptr;
#pragma unroll
    for (int w = 0; w < VPL; ++w) {
      float v = acc[w] * inv + biasR[w];
      v = v > 0.f ? v : expm1f(v);
      u16 h = f2bf(v);
      hh[w] = h;
      if (WLO) hl[w] = f2bf(v - bf2f(h));
    }
  }
}

// ---------------------------------------------------------------------------

extern "C" void kernel_launch(void* const* d_in, const int* in_sizes, int n_in,
                              void* d_out, int out_size, void* d_ws, size_t ws_size,
                              hipStream_t stream) {
  const float* x     = (const float*)d_in[0];
  const int*   ei    = (const int*)d_in[1];
  const float* Wl1   = (const float*)d_in[2];
  const float* bl1   = (const float*)d_in[3];
  const float* Wr1   = (const float*)d_in[4];
  const float* br1   = (const float*)d_in[5];
  const float* att1  = (const float*)d_in[6];
  const float* bias1 = (const float*)d_in[7];
  const float* Wl2   = (const float*)d_in[8];
  const float* bl2   = (const float*)d_in[9];
  const float* Wr2   = (const float*)d_in[10];
  const float* br2   = (const float*)d_in[11];
  const float* att2  = (const float*)d_in[12];
  const float* bias2 = (const float*)d_in[13];
  const float* Wjk   = (const float*)d_in[14];
  const float* bjk   = (const float*)d_in[15];
  float* out = (float*)d_out;

  const int Nn = in_sizes[0] / 128;   // 20000
  const int E  = in_sizes[1] / 2;     // 320000
  const int ET = E + Nn;              // 340000

  const size_t nx = (size_t)Nn * 128;   // 2,560,000

  // transposed-weight region offsets (elements)
  const size_t oWl1T = 0;
  const size_t oWr1T = 65536;
  const size_t oWl2T = 131072;
  const size_t oWr2T = 262144;
  const size_t oWjkT = 393216;
  const size_t nwsplit = 507904;

  // workspace layout (~110 MB)
  char* ws = (char*)d_ws;
  size_t off = 0;
  u16* XH = (u16*)(ws + off); off += nx * 2;
  u16* XL = (u16*)(ws + off); off += nx * 2;
  u16* WTH = (u16*)(ws + off); off += nwsplit * 2;
  u16* WTL = (u16*)(ws + off); off += nwsplit * 2;
  u16* XLR1 = (u16*)(ws + off);                 // [N][1024] bf16 (L1)
  u16* XLR2 = XLR1;                             // [N][512]  bf16 (L2, sequential reuse)
  off += (size_t)Nn * 1024 * 2;
  u16* H1h = (u16*)(ws + off); off += (size_t)Nn * 512 * 2;
  u16* H1l = (u16*)(ws + off); off += (size_t)Nn * 512 * 2;
  u16* H2h = (u16*)(ws + off); off += (size_t)Nn * 256 * 2;
  int* rowptr = (int*)(ws + off); off += (size_t)(Nn + 1) * 4;
  int* cur    = (int*)(ws + off); off += (size_t)Nn * 4;
  int* srcs   = (int*)(ws + off); off += (size_t)ET * 4;

  const int mblocks = (Nn + 127) / 128;   // 157
  const int nodeblocks = (Nn + 3) / 4;    // 1 wave per node, 4 waves/block

  // ---------------- split + transpose + CSR build ----------------
  splitx_kernel<<<((int)nx + 255) / 256, 256, 0, stream>>>(x, XH, XL, (int)nx);
  wsplit_kernel<<<((int)nwsplit + 255) / 256, 256, 0, stream>>>(
      Wl1, Wr1, Wl2, Wr2, Wjk, WTH, WTL);
  hipMemsetAsync(cur, 0, (size_t)Nn * 4, stream);
  hist_kernel<<<(ET + 255) / 256, 256, 0, stream>>>(ei, E, ET, cur);
  scan_kernel<<<1, 1024, 0, stream>>>(cur, rowptr, Nn);
  hipMemsetAsync(cur, 0, (size_t)Nn * 4, stream);
  scatter_kernel<<<(ET + 255) / 256, 256, 0, stream>>>(ei, E, ET, rowptr, cur, srcs);

  // ---------------- Layer 1 ----------------
  dim3 g1(mblocks, 512 / 64);
  gemm3t_kernel<true><<<g1, 256, 0, stream>>>(
      XH, 128, 128, XH, 128, 128, XL, 128, 128,
      WTH + oWl1T, WTL + oWl1T, WTH + oWl1T, 128, bl1,
      XLR1, 1024, 0, Nn);
  gemm3t_kernel<true><<<g1, 256, 0, stream>>>(
      XH, 128, 128, XH, 128, 128, XL, 128, 128,
      WTH + oWr1T, WTL + oWr1T, WTH + oWr1T, 128, br1,
      XLR1, 1024, 512, Nn);
  gat_node_kernel<64, true><<<nodeblocks, 256, 0, stream>>>(
      XLR1, rowptr, srcs, att1, bias1, H1h, H1l, Nn);

  // ---------------- Layer 2 ----------------
  dim3 g2(mblocks, 256 / 64);
  gemm3t_kernel<true><<<g2, 256, 0, stream>>>(
      H1h, 512, 512, H1h, 512, 512, H1l, 512, 512,
      WTH + oWl2T, WTL + oWl2T, WTH + oWl2T, 512, bl2,
      XLR2, 512, 0, Nn);
  gemm3t_kernel<true><<<g2, 256, 0, stream>>>(
      H1h, 512, 512, H1h, 512, 512, H1l, 512, 512,
      WTH + oWr2T, WTL + oWr2T, WTH + oWr2T, 512, br2,
      XLR2, 512, 256, Nn);
  gat_node_kernel<32, false><<<nodeblocks, 256, 0, stream>>>(
      XLR2, rowptr, srcs, att2, bias2, H2h, nullptr, Nn);

  // ---------------- JK linear: out = [x|h1|h2] @ Wjk + bjk (hi-only) --------
  dim3 g3(mblocks, 128 / 64);
  gemm3t_kernel<false><<<g3, 256, 0, stream>>>(
      XH, 128, 128, H1h, 512, 512, H2h, 256, 256,
      WTH + oWjkT, WTH + oWjkT + 128, WTH + oWjkT + 640, 896, bjk,
      out, 128, 0, Nn);
}

// Round 6
// 506.894 us; speedup vs baseline: 1.2999x; 1.2999x over previous
//
#include <hip/hip_runtime.h>

typedef unsigned short u16;
typedef __attribute__((ext_vector_type(8))) short bf16x8;
typedef __attribute__((ext_vector_type(4))) float f32x4;

__device__ __forceinline__ float bf2f(u16 u) { return __uint_as_float(((unsigned)u) << 16); }
__device__ __forceinline__ u16 f2bf(float f) {
  unsigned u = __float_as_uint(f);
  u += 0x7fffu + ((u >> 16) & 1u);   // RNE
  return (u16)(u >> 16);
}
__device__ __forceinline__ void bf2x2(unsigned w, float& lo, float& hi) {
  lo = __uint_as_float(w << 16);
  hi = __uint_as_float(w & 0xffff0000u);
}

// ---------------------------------------------------------------------------
// Split x (f32) -> hi/lo bf16
// ---------------------------------------------------------------------------
__global__ __launch_bounds__(256) void splitx_kernel(
    const float* __restrict__ x, u16* __restrict__ XH, u16* __restrict__ XL, int n)
{
  int i = blockIdx.x * 256 + threadIdx.x;
  if (i >= n) return;
  float v = x[i];
  u16 h = f2bf(v);
  XH[i] = h;
  XL[i] = f2bf(v - bf2f(h));
}

// ---------------------------------------------------------------------------
// Transpose+split the 5 weight matrices: WT[n*K+k] = split(W[k*N+n]).
// ---------------------------------------------------------------------------
__global__ __launch_bounds__(256) void wsplit_kernel(
    const float* __restrict__ w0, const float* __restrict__ w1,
    const float* __restrict__ w2, const float* __restrict__ w3,
    const float* __restrict__ w4,
    u16* __restrict__ WTH, u16* __restrict__ WTL)
{
  int i = blockIdx.x * 256 + threadIdx.x;
  if (i >= 507904) return;
  const float* src; int j = i, K, N;
  if (j < 65536)       { src = w0; K = 128; N = 512; }
  else if (j < 131072) { src = w1; K = 128; N = 512; j -= 65536; }
  else if (j < 262144) { src = w2; K = 512; N = 256; j -= 131072; }
  else if (j < 393216) { src = w3; K = 512; N = 256; j -= 262144; }
  else                 { src = w4; K = 896; N = 128; j -= 393216; }
  int n = j / K, k = j - n * K;
  float v = src[(size_t)k * N + n];
  u16 h = f2bf(v);
  WTH[i] = h;
  WTL[i] = f2bf(v - bf2f(h));
}

// ---------------------------------------------------------------------------
// CSR build: histogram -> exclusive scan -> scatter srcs by dst
// ---------------------------------------------------------------------------
__global__ __launch_bounds__(256) void hist_kernel(
    const int* __restrict__ ei, int E, int ET, int* __restrict__ cnt)
{
  int e = blockIdx.x * 256 + threadIdx.x;
  if (e >= ET) return;
  int d = (e < E) ? ei[E + e] : (e - E);
  atomicAdd(&cnt[d], 1);
}

__global__ __launch_bounds__(1024) void scan_kernel(
    const int* __restrict__ cnt, int* __restrict__ rowptr, int n)
{
  __shared__ int buf[1024];
  __shared__ int carry;
  if (threadIdx.x == 0) carry = 0;
  __syncthreads();
  for (int base = 0; base < n; base += 1024) {
    int i = base + threadIdx.x;
    int v = (i < n) ? cnt[i] : 0;
    buf[threadIdx.x] = v;
    __syncthreads();
    for (int ofs = 1; ofs < 1024; ofs <<= 1) {
      int t = (threadIdx.x >= ofs) ? buf[threadIdx.x - ofs] : 0;
      __syncthreads();
      buf[threadIdx.x] += t;
      __syncthreads();
    }
    int incl = buf[threadIdx.x];
    int c = carry;
    if (i < n) rowptr[i] = c + incl - v;
    int total = buf[1023];
    __syncthreads();
    if (threadIdx.x == 0) carry = c + total;
    __syncthreads();
  }
  if (threadIdx.x == 0) rowptr[n] = carry;
}

__global__ __launch_bounds__(256) void scatter_kernel(
    const int* __restrict__ ei, int E, int ET,
    const int* __restrict__ rowptr, int* __restrict__ cur, int* __restrict__ srcs)
{
  int e = blockIdx.x * 256 + threadIdx.x;
  if (e >= ET) return;
  int s, d;
  if (e < E) { s = ei[e]; d = ei[E + e]; } else { s = e - E; d = s; }
  int pos = rowptr[d] + atomicAdd(&cur[d], 1);
  srcs[pos] = s;
}

// ---------------------------------------------------------------------------
// GEMM v3: C[M, coff:coff+Nc] = sum_s A_s[M,K_s] @ B_s + bias.
// B given TRANSPOSED (BT[n][k], row stride ldbt). Block tile 128x128, 4 waves
// (each 32 rows x 128 cols). B-tile (128n x 32k) double-buffered in LDS,
// staged with vectorized uint4 loads (2 x 16B/thread/step); one barrier per
// k-step. A fragments read directly from global (contiguous 16B/lane).
// Per wave per k-step: 2 A loads + 8 ds_read_b128 + 16 MFMA 16x16x32.
// ---------------------------------------------------------------------------
template<bool BF16OUT>
__global__ __launch_bounds__(256) void gemm3t_kernel(
    const u16* __restrict__ A0, int lda0, int K0,
    const u16* __restrict__ A1, int lda1, int K1,
    const u16* __restrict__ A2, int lda2, int K2,
    const u16* __restrict__ BT0, const u16* __restrict__ BT1, const u16* __restrict__ BT2,
    int ldbt,
    const float* __restrict__ bias,
    void* __restrict__ Cv, int ldc, int coff,
    int M)
{
  __shared__ u16 ldsB[2][128 * 40];
  const int tid  = threadIdx.x;
  const int lane = tid & 63;
  const int wid  = tid >> 6;
  const int quad = lane >> 4;
  const int r16  = lane & 15;
  const int m0   = blockIdx.x * 128;
  const int n0   = blockIdx.y * 128;

  f32x4 acc[2][8];
#pragma unroll
  for (int h = 0; h < 2; ++h)
#pragma unroll
    for (int nc = 0; nc < 8; ++nc) acc[h][nc] = (f32x4){0.f, 0.f, 0.f, 0.f};

  const u16* As[3]  = {A0, A1, A2};
  const u16* BTs[3] = {BT0, BT1, BT2};
  const int  Ks[3]  = {K0, K1, K2};
  const int  lds_[3] = {lda0, lda1, lda2};

  // staging: thread tid covers rows (tid>>2) and 64+(tid>>2), k-chunk (tid&3)*8
  const int srow = tid >> 2;
  const int skq  = (tid & 3) * 8;

#pragma unroll
  for (int s = 0; s < 3; ++s) {
    const int K = Ks[s];
    if (K == 0) continue;
    const u16* A  = As[s];
    const u16* BT = BTs[s];
    const int lda = lds_[s];
    int ar0 = m0 + wid * 32 + r16;      if (ar0 >= M) ar0 = M - 1;
    int ar1 = m0 + wid * 32 + 16 + r16; if (ar1 >= M) ar1 = M - 1;
    const u16* ap0 = A + (size_t)ar0 * lda + quad * 8;
    const u16* ap1 = A + (size_t)ar1 * lda + quad * 8;
    const u16* bs0 = BT + (size_t)(n0 + srow) * ldbt + skq;
    const u16* bs1 = BT + (size_t)(n0 + 64 + srow) * ldbt + skq;

    // prologue: stage k0=0 tile into buf 0
    uint4 t0 = *reinterpret_cast<const uint4*>(bs0);
    uint4 t1 = *reinterpret_cast<const uint4*>(bs1);
    __syncthreads();   // previous segment's reads of buf0 done
    *reinterpret_cast<uint4*>(&ldsB[0][srow * 40 + skq])        = t0;
    *reinterpret_cast<uint4*>(&ldsB[0][(64 + srow) * 40 + skq]) = t1;
    __syncthreads();

    int cur = 0;
    for (int k0 = 0; k0 < K; k0 += 32) {
      const bool more = (k0 + 32 < K);
      uint4 n0v, n1v;
      if (more) {
        n0v = *reinterpret_cast<const uint4*>(bs0 + k0 + 32);
        n1v = *reinterpret_cast<const uint4*>(bs1 + k0 + 32);
      }
      bf16x8 a0 = *reinterpret_cast<const bf16x8*>(ap0 + k0);
      bf16x8 a1 = *reinterpret_cast<const bf16x8*>(ap1 + k0);
#pragma unroll
      for (int nc = 0; nc < 8; ++nc) {
        bf16x8 b = *reinterpret_cast<const bf16x8*>(&ldsB[cur][(nc * 16 + r16) * 40 + quad * 8]);
        acc[0][nc] = __builtin_amdgcn_mfma_f32_16x16x32_bf16(a0, b, acc[0][nc], 0, 0, 0);
        acc[1][nc] = __builtin_amdgcn_mfma_f32_16x16x32_bf16(a1, b, acc[1][nc], 0, 0, 0);
      }
      if (more) {
        *reinterpret_cast<uint4*>(&ldsB[cur ^ 1][srow * 40 + skq])        = n0v;
        *reinterpret_cast<uint4*>(&ldsB[cur ^ 1][(64 + srow) * 40 + skq]) = n1v;
        __syncthreads();
        cur ^= 1;
      }
    }
  }

#pragma unroll
  for (int nc = 0; nc < 8; ++nc) {
    const int col = n0 + nc * 16 + r16;
    const float bv = bias ? bias[col] : 0.f;
#pragma unroll
    for (int half = 0; half < 2; ++half) {
#pragma unroll
      for (int r = 0; r < 4; ++r) {
        int m = m0 + wid * 32 + half * 16 + quad * 4 + r;
        if (m < M) {
          float v = acc[half][nc][r] + bv;
          if (BF16OUT) ((u16*)Cv)[(size_t)m * ldc + coff + col] = f2bf(v);
          else         ((float*)Cv)[(size_t)m * ldc + coff + col] = v;
        }
      }
    }
  }
}

// ---------------------------------------------------------------------------
// Fused GATv2 aggregation (bf16 XLR): one wave per dst node, online softmax
// per head, register accumulation. XLR row (u16): [xl(0..D-1) | xr(D..2D-1)].
// ---------------------------------------------------------------------------
template<int VPL>
__device__ __forceinline__ void load_row(const u16* p, float* dst) {
  if constexpr (VPL == 8) {
    uint4 t = *reinterpret_cast<const uint4*>(p);
    bf2x2(t.x, dst[0], dst[1]); bf2x2(t.y, dst[2], dst[3]);
    bf2x2(t.z, dst[4], dst[5]); bf2x2(t.w, dst[6], dst[7]);
  } else {
    uint2 t = *reinterpret_cast<const uint2*>(p);
    bf2x2(t.x, dst[0], dst[1]); bf2x2(t.y, dst[2], dst[3]);
  }
}

template<int C, bool WLO>
__global__ __launch_bounds__(256) void gat_node_kernel(
    const u16* __restrict__ XLR,
    const int* __restrict__ rowptr, const int* __restrict__ srcs,
    const float* __restrict__ att, const float* __restrict__ bias,
    u16* __restrict__ Hh, u16* __restrict__ Hl, int Nn)
{
  constexpr int D = C * 8;
  constexpr int VPL = D / 64;          // 8 (C=64) or 4 (C=32)
  const int lane = threadIdx.x & 63;
  const int wv  = (blockIdx.x * 256 + threadIdx.x) >> 6;
  const int nwv = (gridDim.x * 256) >> 6;

  float attR[VPL], biasR[VPL];
#pragma unroll
  for (int w = 0; w < VPL; ++w) {
    attR[w]  = att[lane * VPL + w];
    biasR[w] = bias[lane * VPL + w];
  }

  for (int d = wv; d < Nn; d += nwv) {
    float xrR[VPL];
    load_row<VPL>(XLR + (size_t)d * (2 * D) + D + lane * VPL, xrR);

    const int jb = rowptr[d], je = rowptr[d + 1];
    float m = -INFINITY, den = 0.f;
    float acc[VPL];
#pragma unroll
    for (int w = 0; w < VPL; ++w) acc[w] = 0.f;

    float xlR[VPL];
    load_row<VPL>(XLR + (size_t)srcs[jb] * (2 * D) + lane * VPL, xlR);

    for (int j = jb; j < je; ++j) {
      float xlN[VPL];
      if (j + 1 < je)
        load_row<VPL>(XLR + (size_t)srcs[j + 1] * (2 * D) + lane * VPL, xlN);
      float p = 0.f;
#pragma unroll
      for (int w = 0; w < VPL; ++w) {
        float v = xlR[w] + xrR[w];
        v = v > 0.f ? v : 0.2f * v;
        p += v * attR[w];
      }
      p += __shfl_xor(p, 1);
      p += __shfl_xor(p, 2);
      p += __shfl_xor(p, 4);              // logit for this lane's head
      const float mn = fmaxf(m, p);
      const float f  = __expf(m - mn);    // m=-inf first iter -> f=0
      const float pe = __expf(p - mn);
      den = den * f + pe;
#pragma unroll
      for (int w = 0; w < VPL; ++w) acc[w] = acc[w] * f + pe * xlR[w];
      m = mn;
      if (j + 1 < je) {
#pragma unroll
        for (int w = 0; w < VPL; ++w) xlR[w] = xlN[w];
      }
    }

    const float inv = 1.f / den;
    u16* hh = Hh + (size_t)d * D + lane * VPL;
    u16* hl = WLO ? (Hl + (size_t)d * D + lane * VPL) : nullptr;
#pragma unroll
    for (int w = 0; w < VPL; ++w) {
      float v = acc[w] * inv + biasR[w];
      v = v > 0.f ? v : expm1f(v);
      u16 h = f2bf(v);
      hh[w] = h;
      if (WLO) hl[w] = f2bf(v - bf2f(h));
    }
  }
}

// ---------------------------------------------------------------------------

extern "C" void kernel_launch(void* const* d_in, const int* in_sizes, int n_in,
                              void* d_out, int out_size, void* d_ws, size_t ws_size,
                              hipStream_t stream) {
  const float* x     = (const float*)d_in[0];
  const int*   ei    = (const int*)d_in[1];
  const float* Wl1   = (const float*)d_in[2];
  const float* bl1   = (const float*)d_in[3];
  const float* Wr1   = (const float*)d_in[4];
  const float* br1   = (const float*)d_in[5];
  const float* att1  = (const float*)d_in[6];
  const float* bias1 = (const float*)d_in[7];
  const float* Wl2   = (const float*)d_in[8];
  const float* bl2   = (const float*)d_in[9];
  const float* Wr2   = (const float*)d_in[10];
  const float* br2   = (const float*)d_in[11];
  const float* att2  = (const float*)d_in[12];
  const float* bias2 = (const float*)d_in[13];
  const float* Wjk   = (const float*)d_in[14];
  const float* bjk   = (const float*)d_in[15];
  float* out = (float*)d_out;

  const int Nn = in_sizes[0] / 128;   // 20000
  const int E  = in_sizes[1] / 2;     // 320000
  const int ET = E + Nn;              // 340000

  const size_t nx = (size_t)Nn * 128;   // 2,560,000

  // transposed-weight region offsets (elements)
  const size_t oWl1T = 0;
  const size_t oWr1T = 65536;
  const size_t oWl2T = 131072;
  const size_t oWr2T = 262144;
  const size_t oWjkT = 393216;
  const size_t nwsplit = 507904;

  // workspace layout (~110 MB)
  char* ws = (char*)d_ws;
  size_t off = 0;
  u16* XH = (u16*)(ws + off); off += nx * 2;
  u16* XL = (u16*)(ws + off); off += nx * 2;
  u16* WTH = (u16*)(ws + off); off += nwsplit * 2;
  u16* WTL = (u16*)(ws + off); off += nwsplit * 2;
  u16* XLR1 = (u16*)(ws + off);                 // [N][1024] bf16 (L1)
  u16* XLR2 = XLR1;                             // [N][512]  bf16 (L2, sequential reuse)
  off += (size_t)Nn * 1024 * 2;
  u16* H1h = (u16*)(ws + off); off += (size_t)Nn * 512 * 2;
  u16* H1l = (u16*)(ws + off); off += (size_t)Nn * 512 * 2;
  u16* H2h = (u16*)(ws + off); off += (size_t)Nn * 256 * 2;
  int* rowptr = (int*)(ws + off); off += (size_t)(Nn + 1) * 4;
  int* cur    = (int*)(ws + off); off += (size_t)Nn * 4;
  int* srcs   = (int*)(ws + off); off += (size_t)ET * 4;

  const int mblocks = (Nn + 127) / 128;   // 157
  const int nodeblocks = (Nn + 3) / 4;    // 1 wave per node, 4 waves/block

  // ---------------- split + transpose + CSR build ----------------
  splitx_kernel<<<((int)nx + 255) / 256, 256, 0, stream>>>(x, XH, XL, (int)nx);
  wsplit_kernel<<<((int)nwsplit + 255) / 256, 256, 0, stream>>>(
      Wl1, Wr1, Wl2, Wr2, Wjk, WTH, WTL);
  hipMemsetAsync(cur, 0, (size_t)Nn * 4, stream);
  hist_kernel<<<(ET + 255) / 256, 256, 0, stream>>>(ei, E, ET, cur);
  scan_kernel<<<1, 1024, 0, stream>>>(cur, rowptr, Nn);
  hipMemsetAsync(cur, 0, (size_t)Nn * 4, stream);
  scatter_kernel<<<(ET + 255) / 256, 256, 0, stream>>>(ei, E, ET, rowptr, cur, srcs);

  // ---------------- Layer 1 ----------------
  dim3 g1(mblocks, 512 / 128);
  gemm3t_kernel<true><<<g1, 256, 0, stream>>>(
      XH, 128, 128, XH, 128, 128, XL, 128, 128,
      WTH + oWl1T, WTL + oWl1T, WTH + oWl1T, 128, bl1,
      XLR1, 1024, 0, Nn);
  gemm3t_kernel<true><<<g1, 256, 0, stream>>>(
      XH, 128, 128, XH, 128, 128, XL, 128, 128,
      WTH + oWr1T, WTL + oWr1T, WTH + oWr1T, 128, br1,
      XLR1, 1024, 512, Nn);
  gat_node_kernel<64, true><<<nodeblocks, 256, 0, stream>>>(
      XLR1, rowptr, srcs, att1, bias1, H1h, H1l, Nn);

  // ---------------- Layer 2 ----------------
  dim3 g2(mblocks, 256 / 128);
  gemm3t_kernel<true><<<g2, 256, 0, stream>>>(
      H1h, 512, 512, H1h, 512, 512, H1l, 512, 512,
      WTH + oWl2T, WTL + oWl2T, WTH + oWl2T, 512, bl2,
      XLR2, 512, 0, Nn);
  gemm3t_kernel<true><<<g2, 256, 0, stream>>>(
      H1h, 512, 512, H1h, 512, 512, H1l, 512, 512,
      WTH + oWr2T, WTL + oWr2T, WTH + oWr2T, 512, br2,
      XLR2, 512, 256, Nn);
  gat_node_kernel<32, false><<<nodeblocks, 256, 0, stream>>>(
      XLR2, rowptr, srcs, att2, bias2, H2h, nullptr, Nn);

  // ---------------- JK linear: out = [x|h1|h2] @ Wjk + bjk (hi-only) --------
  dim3 g3(mblocks, 128 / 128);
  gemm3t_kernel<false><<<g3, 256, 0, stream>>>(
      XH, 128, 128, H1h, 512, 512, H2h, 256, 256,
      WTH + oWjkT, WTH + oWjkT + 128, WTH + oWjkT + 640, 896, bjk,
      out, 128, 0, Nn);
}

// Round 7
// 473.323 us; speedup vs baseline: 1.3921x; 1.0709x over previous
//
#include <hip/hip_runtime.h>

typedef unsigned short u16;
typedef __attribute__((ext_vector_type(8))) short bf16x8;
typedef __attribute__((ext_vector_type(4))) float f32x4;

__device__ __forceinline__ float bf2f(u16 u) { return __uint_as_float(((unsigned)u) << 16); }
__device__ __forceinline__ u16 f2bf(float f) {
  unsigned u = __float_as_uint(f);
  u += 0x7fffu + ((u >> 16) & 1u);   // RNE
  return (u16)(u >> 16);
}
__device__ __forceinline__ void bf2x2(unsigned w, float& lo, float& hi) {
  lo = __uint_as_float(w << 16);
  hi = __uint_as_float(w & 0xffff0000u);
}

// ---------------------------------------------------------------------------
// Split x (f32) -> hi/lo bf16
// ---------------------------------------------------------------------------
__global__ __launch_bounds__(256) void splitx_kernel(
    const float* __restrict__ x, u16* __restrict__ XH, u16* __restrict__ XL, int n)
{
  int i = blockIdx.x * 256 + threadIdx.x;
  if (i >= n) return;
  float v = x[i];
  u16 h = f2bf(v);
  XH[i] = h;
  XL[i] = f2bf(v - bf2f(h));
}

// ---------------------------------------------------------------------------
// Transpose+split the 5 weight matrices: WT[n*K+k] = split(W[k*N+n]).
// ---------------------------------------------------------------------------
__global__ __launch_bounds__(256) void wsplit_kernel(
    const float* __restrict__ w0, const float* __restrict__ w1,
    const float* __restrict__ w2, const float* __restrict__ w3,
    const float* __restrict__ w4,
    u16* __restrict__ WTH, u16* __restrict__ WTL)
{
  int i = blockIdx.x * 256 + threadIdx.x;
  if (i >= 507904) return;
  const float* src; int j = i, K, N;
  if (j < 65536)       { src = w0; K = 128; N = 512; }
  else if (j < 131072) { src = w1; K = 128; N = 512; j -= 65536; }
  else if (j < 262144) { src = w2; K = 512; N = 256; j -= 131072; }
  else if (j < 393216) { src = w3; K = 512; N = 256; j -= 262144; }
  else                 { src = w4; K = 896; N = 128; j -= 393216; }
  int n = j / K, k = j - n * K;
  float v = src[(size_t)k * N + n];
  u16 h = f2bf(v);
  WTH[i] = h;
  WTL[i] = f2bf(v - bf2f(h));
}

// ---------------------------------------------------------------------------
// CSR build: histogram -> exclusive scan -> scatter srcs by dst
// ---------------------------------------------------------------------------
__global__ __launch_bounds__(256) void hist_kernel(
    const int* __restrict__ ei, int E, int ET, int* __restrict__ cnt)
{
  int e = blockIdx.x * 256 + threadIdx.x;
  if (e >= ET) return;
  int d = (e < E) ? ei[E + e] : (e - E);
  atomicAdd(&cnt[d], 1);
}

__global__ __launch_bounds__(1024) void scan_kernel(
    const int* __restrict__ cnt, int* __restrict__ rowptr, int n)
{
  __shared__ int buf[1024];
  __shared__ int carry;
  if (threadIdx.x == 0) carry = 0;
  __syncthreads();
  for (int base = 0; base < n; base += 1024) {
    int i = base + threadIdx.x;
    int v = (i < n) ? cnt[i] : 0;
    buf[threadIdx.x] = v;
    __syncthreads();
    for (int ofs = 1; ofs < 1024; ofs <<= 1) {
      int t = (threadIdx.x >= ofs) ? buf[threadIdx.x - ofs] : 0;
      __syncthreads();
      buf[threadIdx.x] += t;
      __syncthreads();
    }
    int incl = buf[threadIdx.x];
    int c = carry;
    if (i < n) rowptr[i] = c + incl - v;
    int total = buf[1023];
    __syncthreads();
    if (threadIdx.x == 0) carry = c + total;
    __syncthreads();
  }
  if (threadIdx.x == 0) rowptr[n] = carry;
}

__global__ __launch_bounds__(256) void scatter_kernel(
    const int* __restrict__ ei, int E, int ET,
    const int* __restrict__ rowptr, int* __restrict__ cur, int* __restrict__ srcs)
{
  int e = blockIdx.x * 256 + threadIdx.x;
  if (e >= ET) return;
  int s, d;
  if (e < E) { s = ei[e]; d = ei[E + e]; } else { s = e - E; d = s; }
  int pos = rowptr[d] + atomicAdd(&cur[d], 1);
  srcs[pos] = s;
}

// ---------------------------------------------------------------------------
// GEMM v4: C[M, coff:coff+Nc] = sum_s A_s[M,K_s] @ B_s + bias.
// B given TRANSPOSED (BT[n][k], row stride ldbt). Block = 4 waves, each
// RW*16 rows x 128 cols (RW=2 -> 128-row block, RW=1 -> 64-row block).
// B-tile (128n x 32k) double-buffered in LDS, staged with uint4 loads;
// one barrier per k-step. A fragments read directly from global.
// ---------------------------------------------------------------------------
template<bool BF16OUT, int RW>
__global__ __launch_bounds__(256) void gemm3t_kernel(
    const u16* __restrict__ A0, int lda0, int K0,
    const u16* __restrict__ A1, int lda1, int K1,
    const u16* __restrict__ A2, int lda2, int K2,
    const u16* __restrict__ BT0, const u16* __restrict__ BT1, const u16* __restrict__ BT2,
    int ldbt,
    const float* __restrict__ bias,
    void* __restrict__ Cv, int ldc, int coff,
    int M)
{
  __shared__ u16 ldsB[2][128 * 40];
  const int tid  = threadIdx.x;
  const int lane = tid & 63;
  const int wid  = tid >> 6;
  const int quad = lane >> 4;
  const int r16  = lane & 15;
  const int m0   = blockIdx.x * (RW * 64);
  const int n0   = blockIdx.y * 128;

  f32x4 acc[RW][8];
#pragma unroll
  for (int h = 0; h < RW; ++h)
#pragma unroll
    for (int nc = 0; nc < 8; ++nc) acc[h][nc] = (f32x4){0.f, 0.f, 0.f, 0.f};

  const u16* As[3]  = {A0, A1, A2};
  const u16* BTs[3] = {BT0, BT1, BT2};
  const int  Ks[3]  = {K0, K1, K2};
  const int  lds_[3] = {lda0, lda1, lda2};

  const int srow = tid >> 2;
  const int skq  = (tid & 3) * 8;

#pragma unroll
  for (int s = 0; s < 3; ++s) {
    const int K = Ks[s];
    if (K == 0) continue;
    const u16* A  = As[s];
    const u16* BT = BTs[s];
    const int lda = lds_[s];
    const u16* ap[RW];
#pragma unroll
    for (int h = 0; h < RW; ++h) {
      int ar = m0 + wid * (RW * 16) + h * 16 + r16;
      if (ar >= M) ar = M - 1;
      ap[h] = A + (size_t)ar * lda + quad * 8;
    }
    const u16* bs0 = BT + (size_t)(n0 + srow) * ldbt + skq;
    const u16* bs1 = BT + (size_t)(n0 + 64 + srow) * ldbt + skq;

    // prologue: stage k0=0 tile into buf 0
    uint4 t0 = *reinterpret_cast<const uint4*>(bs0);
    uint4 t1 = *reinterpret_cast<const uint4*>(bs1);
    __syncthreads();   // previous segment's reads done
    *reinterpret_cast<uint4*>(&ldsB[0][srow * 40 + skq])        = t0;
    *reinterpret_cast<uint4*>(&ldsB[0][(64 + srow) * 40 + skq]) = t1;
    __syncthreads();

    int cur = 0;
    for (int k0 = 0; k0 < K; k0 += 32) {
      const bool more = (k0 + 32 < K);
      uint4 n0v, n1v;
      if (more) {
        n0v = *reinterpret_cast<const uint4*>(bs0 + k0 + 32);
        n1v = *reinterpret_cast<const uint4*>(bs1 + k0 + 32);
      }
      bf16x8 a[RW];
#pragma unroll
      for (int h = 0; h < RW; ++h)
        a[h] = *reinterpret_cast<const bf16x8*>(ap[h] + k0);
#pragma unroll
      for (int nc = 0; nc < 8; ++nc) {
        bf16x8 b = *reinterpret_cast<const bf16x8*>(&ldsB[cur][(nc * 16 + r16) * 40 + quad * 8]);
#pragma unroll
        for (int h = 0; h < RW; ++h)
          acc[h][nc] = __builtin_amdgcn_mfma_f32_16x16x32_bf16(a[h], b, acc[h][nc], 0, 0, 0);
      }
      if (more) {
        *reinterpret_cast<uint4*>(&ldsB[cur ^ 1][srow * 40 + skq])        = n0v;
        *reinterpret_cast<uint4*>(&ldsB[cur ^ 1][(64 + srow) * 40 + skq]) = n1v;
        __syncthreads();
        cur ^= 1;
      }
    }
  }

#pragma unroll
  for (int nc = 0; nc < 8; ++nc) {
    const int col = n0 + nc * 16 + r16;
    const float bv = bias ? bias[col] : 0.f;
#pragma unroll
    for (int h = 0; h < RW; ++h) {
#pragma unroll
      for (int r = 0; r < 4; ++r) {
        int m = m0 + wid * (RW * 16) + h * 16 + quad * 4 + r;
        if (m < M) {
          float v = acc[h][nc][r] + bv;
          if (BF16OUT) ((u16*)Cv)[(size_t)m * ldc + coff + col] = f2bf(v);
          else         ((float*)Cv)[(size_t)m * ldc + coff + col] = v;
        }
      }
    }
  }
}

// ---------------------------------------------------------------------------
// Fused GATv2 aggregation (bf16 XLR): one wave per dst node, online softmax
// per head, register accumulation, edges processed in PAIRS for ILP.
// XLR row (u16): [xl(0..D-1) | xr(D..2D-1)].
// ---------------------------------------------------------------------------
template<int VPL>
__device__ __forceinline__ void load_row(const u16* p, float* dst) {
  if constexpr (VPL == 8) {
    uint4 t = *reinterpret_cast<const uint4*>(p);
    bf2x2(t.x, dst[0], dst[1]); bf2x2(t.y, dst[2], dst[3]);
    bf2x2(t.z, dst[4], dst[5]); bf2x2(t.w, dst[6], dst[7]);
  } else {
    uint2 t = *reinterpret_cast<const uint2*>(p);
    bf2x2(t.x, dst[0], dst[1]); bf2x2(t.y, dst[2], dst[3]);
  }
}

template<int C, bool WLO>
__global__ __launch_bounds__(256) void gat_node_kernel(
    const u16* __restrict__ XLR,
    const int* __restrict__ rowptr, const int* __restrict__ srcs,
    const float* __restrict__ att, const float* __restrict__ bias,
    u16* __restrict__ Hh, u16* __restrict__ Hl, int Nn)
{
  constexpr int D = C * 8;
  constexpr int VPL = D / 64;          // 8 (C=64) or 4 (C=32)
  const int lane = threadIdx.x & 63;
  const int wv  = (blockIdx.x * 256 + threadIdx.x) >> 6;
  const int nwv = (gridDim.x * 256) >> 6;

  float attR[VPL], biasR[VPL];
#pragma unroll
  for (int w = 0; w < VPL; ++w) {
    attR[w]  = att[lane * VPL + w];
    biasR[w] = bias[lane * VPL + w];
  }

  for (int d = wv; d < Nn; d += nwv) {
    float xrR[VPL];
    load_row<VPL>(XLR + (size_t)d * (2 * D) + D + lane * VPL, xrR);

    const int jb = rowptr[d], je = rowptr[d + 1];
    float m = -INFINITY, den = 0.f;
    float acc[VPL];
#pragma unroll
    for (int w = 0; w < VPL; ++w) acc[w] = 0.f;

    int j = jb;
    for (; j + 1 < je; j += 2) {
      float xa[VPL], xb[VPL];
      load_row<VPL>(XLR + (size_t)srcs[j]     * (2 * D) + lane * VPL, xa);
      load_row<VPL>(XLR + (size_t)srcs[j + 1] * (2 * D) + lane * VPL, xb);
      float pa = 0.f, pb = 0.f;
#pragma unroll
      for (int w = 0; w < VPL; ++w) {
        float va = xa[w] + xrR[w]; va = fmaxf(va, 0.2f * va); pa += va * attR[w];
        float vb = xb[w] + xrR[w]; vb = fmaxf(vb, 0.2f * vb); pb += vb * attR[w];
      }
      pa += __shfl_xor(pa, 1); pb += __shfl_xor(pb, 1);
      pa += __shfl_xor(pa, 2); pb += __shfl_xor(pb, 2);
      pa += __shfl_xor(pa, 4); pb += __shfl_xor(pb, 4);
      const float mn = fmaxf(m, fmaxf(pa, pb));
      const float f  = __expf(m - mn);     // m=-inf first iter -> 0
      const float ea = __expf(pa - mn);
      const float eb = __expf(pb - mn);
      den = den * f + ea + eb;
#pragma unroll
      for (int w = 0; w < VPL; ++w)
        acc[w] = acc[w] * f + ea * xa[w] + eb * xb[w];
      m = mn;
    }
    if (j < je) {
      float xa[VPL];
      load_row<VPL>(XLR + (size_t)srcs[j] * (2 * D) + lane * VPL, xa);
      float pa = 0.f;
#pragma unroll
      for (int w = 0; w < VPL; ++w) {
        float va = xa[w] + xrR[w]; va = fmaxf(va, 0.2f * va); pa += va * attR[w];
      }
      pa += __shfl_xor(pa, 1);
      pa += __shfl_xor(pa, 2);
      pa += __shfl_xor(pa, 4);
      const float mn = fmaxf(m, pa);
      const float f  = __expf(m - mn);
      const float ea = __expf(pa - mn);
      den = den * f + ea;
#pragma unroll
      for (int w = 0; w < VPL; ++w) acc[w] = acc[w] * f + ea * xa[w];
      m = mn;
    }

    const float inv = 1.f / den;
    u16* hh = Hh + (size_t)d * D + lane * VPL;
    u16* hl = WLO ? (Hl + (size_t)d * D + lane * VPL) : nullptr;
#pragma unroll
    for (int w = 0; w < VPL; ++w) {
      float v = acc[w] * inv + biasR[w];
      v = v > 0.f ? v : expm1f(v);
      u16 h = f2bf(v);
      hh[w] = h;
      if (WLO) hl[w] = f2bf(v - bf2f(h));
    }
  }
}

// ---------------------------------------------------------------------------

extern "C" void kernel_launch(void* const* d_in, const int* in_sizes, int n_in,
                              void* d_out, int out_size, void* d_ws, size_t ws_size,
                              hipStream_t stream) {
  const float* x     = (const float*)d_in[0];
  const int*   ei    = (const int*)d_in[1];
  const float* Wl1   = (const float*)d_in[2];
  const float* bl1   = (const float*)d_in[3];
  const float* Wr1   = (const float*)d_in[4];
  const float* br1   = (const float*)d_in[5];
  const float* att1  = (const float*)d_in[6];
  const float* bias1 = (const float*)d_in[7];
  const float* Wl2   = (const float*)d_in[8];
  const float* bl2   = (const float*)d_in[9];
  const float* Wr2   = (const float*)d_in[10];
  const float* br2   = (const float*)d_in[11];
  const float* att2  = (const float*)d_in[12];
  const float* bias2 = (const float*)d_in[13];
  const float* Wjk   = (const float*)d_in[14];
  const float* bjk   = (const float*)d_in[15];
  float* out = (float*)d_out;

  const int Nn = in_sizes[0] / 128;   // 20000
  const int E  = in_sizes[1] / 2;     // 320000
  const int ET = E + Nn;              // 340000

  const size_t nx = (size_t)Nn * 128;   // 2,560,000

  // transposed-weight region offsets (elements)
  const size_t oWl1T = 0;
  const size_t oWr1T = 65536;
  const size_t oWl2T = 131072;
  const size_t oWr2T = 262144;
  const size_t oWjkT = 393216;
  const size_t nwsplit = 507904;

  // workspace layout (~110 MB)
  char* ws = (char*)d_ws;
  size_t off = 0;
  u16* XH = (u16*)(ws + off); off += nx * 2;
  u16* XL = (u16*)(ws + off); off += nx * 2;
  u16* WTH = (u16*)(ws + off); off += nwsplit * 2;
  u16* WTL = (u16*)(ws + off); off += nwsplit * 2;
  u16* XLR1 = (u16*)(ws + off);                 // [N][1024] bf16 (L1)
  u16* XLR2 = XLR1;                             // [N][512]  bf16 (L2, sequential reuse)
  off += (size_t)Nn * 1024 * 2;
  u16* H1h = (u16*)(ws + off); off += (size_t)Nn * 512 * 2;
  u16* H1l = (u16*)(ws + off); off += (size_t)Nn * 512 * 2;
  u16* H2h = (u16*)(ws + off); off += (size_t)Nn * 256 * 2;
  int* rowptr = (int*)(ws + off); off += (size_t)(Nn + 1) * 4;
  int* cur    = (int*)(ws + off); off += (size_t)Nn * 4;
  int* srcs   = (int*)(ws + off); off += (size_t)ET * 4;

  const int m128 = (Nn + 127) / 128;   // 157
  const int m64  = (Nn + 63) / 64;     // 313
  const int nodeblocks = 1536;         // grid-stride, ~3 nodes/wave

  // ---------------- split + transpose + CSR build ----------------
  splitx_kernel<<<((int)nx + 255) / 256, 256, 0, stream>>>(x, XH, XL, (int)nx);
  wsplit_kernel<<<((int)nwsplit + 255) / 256, 256, 0, stream>>>(
      Wl1, Wr1, Wl2, Wr2, Wjk, WTH, WTL);
  hipMemsetAsync(cur, 0, (size_t)Nn * 4, stream);
  hist_kernel<<<(ET + 255) / 256, 256, 0, stream>>>(ei, E, ET, cur);
  scan_kernel<<<1, 1024, 0, stream>>>(cur, rowptr, Nn);
  hipMemsetAsync(cur, 0, (size_t)Nn * 4, stream);
  scatter_kernel<<<(ET + 255) / 256, 256, 0, stream>>>(ei, E, ET, rowptr, cur, srcs);

  // ---------------- Layer 1 ----------------
  dim3 g1(m128, 512 / 128);
  gemm3t_kernel<true, 2><<<g1, 256, 0, stream>>>(
      XH, 128, 128, XH, 128, 128, XL, 128, 128,
      WTH + oWl1T, WTL + oWl1T, WTH + oWl1T, 128, bl1,
      XLR1, 1024, 0, Nn);
  gemm3t_kernel<true, 2><<<g1, 256, 0, stream>>>(
      XH, 128, 128, XH, 128, 128, XL, 128, 128,
      WTH + oWr1T, WTL + oWr1T, WTH + oWr1T, 128, br1,
      XLR1, 1024, 512, Nn);
  gat_node_kernel<64, true><<<nodeblocks, 256, 0, stream>>>(
      XLR1, rowptr, srcs, att1, bias1, H1h, H1l, Nn);

  // ---------------- Layer 2 ----------------
  dim3 g2(m64, 256 / 128);
  gemm3t_kernel<true, 1><<<g2, 256, 0, stream>>>(
      H1h, 512, 512, H1h, 512, 512, H1l, 512, 512,
      WTH + oWl2T, WTL + oWl2T, WTH + oWl2T, 512, bl2,
      XLR2, 512, 0, Nn);
  gemm3t_kernel<true, 1><<<g2, 256, 0, stream>>>(
      H1h, 512, 512, H1h, 512, 512, H1l, 512, 512,
      WTH + oWr2T, WTL + oWr2T, WTH + oWr2T, 512, br2,
      XLR2, 512, 256, Nn);
  gat_node_kernel<32, false><<<nodeblocks, 256, 0, stream>>>(
      XLR2, rowptr, srcs, att2, bias2, H2h, nullptr, Nn);

  // ---------------- JK linear: out = [x|h1|h2] @ Wjk + bjk (hi-only) --------
  dim3 g3(m64, 128 / 128);
  gemm3t_kernel<false, 1><<<g3, 256, 0, stream>>>(
      XH, 128, 128, H1h, 512, 512, H2h, 256, 256,
      WTH + oWjkT, WTH + oWjkT + 128, WTH + oWjkT + 640, 896, bjk,
      out, 128, 0, Nn);
}

// Round 8
// 399.486 us; speedup vs baseline: 1.6494x; 1.1848x over previous
//
#include <hip/hip_runtime.h>

typedef unsigned short u16;
typedef __attribute__((ext_vector_type(8))) short bf16x8;
typedef __attribute__((ext_vector_type(4))) float f32x4;

__device__ __forceinline__ float bf2f(u16 u) { return __uint_as_float(((unsigned)u) << 16); }
__device__ __forceinline__ u16 f2bf(float f) {
  unsigned u = __float_as_uint(f);
  u += 0x7fffu + ((u >> 16) & 1u);   // RNE
  return (u16)(u >> 16);
}
__device__ __forceinline__ void bf2x2(unsigned w, float& lo, float& hi) {
  lo = __uint_as_float(w << 16);
  hi = __uint_as_float(w & 0xffff0000u);
}

// ---------------------------------------------------------------------------
// Fused prep: [0,nx) x->XH (hi only); [nx,nx+507904) weight transpose+split
// (hi+lo); tail 1536: bias concat BC1=[bl1|br1], BC2=[bl2|br2].
// ---------------------------------------------------------------------------
__global__ __launch_bounds__(256) void prep_kernel(
    const float* __restrict__ x,
    const float* __restrict__ w0, const float* __restrict__ w1,
    const float* __restrict__ w2, const float* __restrict__ w3,
    const float* __restrict__ w4,
    const float* __restrict__ bl1, const float* __restrict__ br1,
    const float* __restrict__ bl2, const float* __restrict__ br2,
    u16* __restrict__ XH, u16* __restrict__ WTH, u16* __restrict__ WTL,
    float* __restrict__ BC1, float* __restrict__ BC2,
    int nx, int total)
{
  int i = blockIdx.x * 256 + threadIdx.x;
  if (i >= total) return;
  if (i < nx) { XH[i] = f2bf(x[i]); return; }
  int j = i - nx;
  if (j < 507904) {
    const float* src; int K, N;
    if (j < 65536)       { src = w0; K = 128; N = 512; }
    else if (j < 131072) { src = w1; K = 128; N = 512; j -= 65536; }
    else if (j < 262144) { src = w2; K = 512; N = 256; j -= 131072; }
    else if (j < 393216) { src = w3; K = 512; N = 256; j -= 262144; }
    else                 { src = w4; K = 896; N = 128; j -= 393216; }
    int n = j / K, k = j - n * K;
    float v = src[(size_t)k * N + n];
    u16 h = f2bf(v);
    int o = i - nx;
    WTH[o] = h;
    WTL[o] = f2bf(v - bf2f(h));
    return;
  }
  int j2 = j - 507904;
  if (j2 < 1024) BC1[j2] = (j2 < 512) ? bl1[j2] : br1[j2 - 512];
  else { int t = j2 - 1024; BC2[t] = (t < 256) ? bl2[t] : br2[t - 256]; }
}

// ---------------------------------------------------------------------------
// CSR build: histogram -> exclusive scan (shuffle-based) -> scatter
// ---------------------------------------------------------------------------
__global__ __launch_bounds__(256) void hist_kernel(
    const int* __restrict__ ei, int E, int ET, int* __restrict__ cnt)
{
  int e = blockIdx.x * 256 + threadIdx.x;
  if (e >= ET) return;
  int d = (e < E) ? ei[E + e] : (e - E);
  atomicAdd(&cnt[d], 1);
}

__global__ __launch_bounds__(1024) void scan_kernel(
    const int* __restrict__ cnt, int* __restrict__ rowptr, int n)
{
  __shared__ int wsum[16];
  __shared__ int carry;
  const int tid = threadIdx.x, lane = tid & 63, wv = tid >> 6;
  if (tid == 0) carry = 0;
  __syncthreads();
  for (int base = 0; base < n; base += 1024) {
    int i = base + tid;
    int v = (i < n) ? cnt[i] : 0;
    int s = v;
#pragma unroll
    for (int ofs = 1; ofs < 64; ofs <<= 1) {
      int t = __shfl_up(s, ofs);
      if (lane >= ofs) s += t;
    }
    if (lane == 63) wsum[wv] = s;
    __syncthreads();
    if (wv == 0 && lane < 16) {
      int t = wsum[lane];
#pragma unroll
      for (int ofs = 1; ofs < 16; ofs <<= 1) {
        int u = __shfl_up(t, ofs);
        if (lane >= ofs) t += u;
      }
      wsum[lane] = t;
    }
    __syncthreads();
    int waveoff = (wv == 0) ? 0 : wsum[wv - 1];
    if (i < n) rowptr[i] = carry + waveoff + s - v;
    int tot = wsum[15];
    __syncthreads();
    if (tid == 0) carry += tot;
    __syncthreads();
  }
  if (threadIdx.x == 0) rowptr[n] = carry;
}

__global__ __launch_bounds__(256) void scatter_kernel(
    const int* __restrict__ ei, int E, int ET,
    const int* __restrict__ rowptr, int* __restrict__ cur, int* __restrict__ srcs)
{
  int e = blockIdx.x * 256 + threadIdx.x;
  if (e >= ET) return;
  int s, d;
  if (e < E) { s = ei[e]; d = ei[E + e]; } else { s = e - E; d = s; }
  int pos = rowptr[d] + atomicAdd(&cur[d], 1);
  srcs[pos] = s;
}

// ---------------------------------------------------------------------------
// GEMM v5: C[M, 0:Nc] = sum_s A_s[M,K_s] @ B_s + bias.
// B TRANSPOSED (BT[n][k], row stride ldbt). Block = 4 waves, each wave
// RW*16 rows x 128 cols (block = RW*64 rows x 128 cols). B-tile (128n x 32k)
// double-buffered in LDS via uint4; one barrier per k-step. A from global.
// Per wave per k-step: RW A-loads + 8 ds_read_b128 + 8*RW MFMA 16x16x32.
// ---------------------------------------------------------------------------
template<bool BF16OUT, int RW>
__global__ __launch_bounds__(256, 2) void gemm3t_kernel(
    const u16* __restrict__ A0, int lda0, int K0,
    const u16* __restrict__ A1, int lda1, int K1,
    const u16* __restrict__ A2, int lda2, int K2,
    const u16* __restrict__ BT0, const u16* __restrict__ BT1, const u16* __restrict__ BT2,
    int ldbt,
    const float* __restrict__ bias,
    void* __restrict__ Cv, int ldc,
    int M)
{
  __shared__ u16 ldsB[2][128 * 40];
  const int tid  = threadIdx.x;
  const int lane = tid & 63;
  const int wid  = tid >> 6;
  const int quad = lane >> 4;
  const int r16  = lane & 15;
  const int m0   = blockIdx.x * (RW * 64);
  const int n0   = blockIdx.y * 128;

  f32x4 acc[RW][8];
#pragma unroll
  for (int h = 0; h < RW; ++h)
#pragma unroll
    for (int nc = 0; nc < 8; ++nc) acc[h][nc] = (f32x4){0.f, 0.f, 0.f, 0.f};

  const u16* As[3]  = {A0, A1, A2};
  const u16* BTs[3] = {BT0, BT1, BT2};
  const int  Ks[3]  = {K0, K1, K2};
  const int  lds_[3] = {lda0, lda1, lda2};

  const int srow = tid >> 2;
  const int skq  = (tid & 3) * 8;

#pragma unroll
  for (int s = 0; s < 3; ++s) {
    const int K = Ks[s];
    if (K == 0) continue;
    const u16* A  = As[s];
    const u16* BT = BTs[s];
    const int lda = lds_[s];
    const u16* ap[RW];
#pragma unroll
    for (int h = 0; h < RW; ++h) {
      int ar = m0 + wid * (RW * 16) + h * 16 + r16;
      if (ar >= M) ar = M - 1;
      ap[h] = A + (size_t)ar * lda + quad * 8;
    }
    const u16* bs0 = BT + (size_t)(n0 + srow) * ldbt + skq;
    const u16* bs1 = BT + (size_t)(n0 + 64 + srow) * ldbt + skq;

    // prologue: stage k0=0 tile into buf 0
    uint4 t0 = *reinterpret_cast<const uint4*>(bs0);
    uint4 t1 = *reinterpret_cast<const uint4*>(bs1);
    __syncthreads();   // previous reads of buf0 done
    *reinterpret_cast<uint4*>(&ldsB[0][srow * 40 + skq])        = t0;
    *reinterpret_cast<uint4*>(&ldsB[0][(64 + srow) * 40 + skq]) = t1;
    __syncthreads();

    int cur = 0;
    for (int k0 = 0; k0 < K; k0 += 32) {
      const bool more = (k0 + 32 < K);
      uint4 n0v, n1v;
      if (more) {
        n0v = *reinterpret_cast<const uint4*>(bs0 + k0 + 32);
        n1v = *reinterpret_cast<const uint4*>(bs1 + k0 + 32);
      }
      bf16x8 a[RW];
#pragma unroll
      for (int h = 0; h < RW; ++h)
        a[h] = *reinterpret_cast<const bf16x8*>(ap[h] + k0);
#pragma unroll
      for (int nc = 0; nc < 8; ++nc) {
        bf16x8 b = *reinterpret_cast<const bf16x8*>(&ldsB[cur][(nc * 16 + r16) * 40 + quad * 8]);
#pragma unroll
        for (int h = 0; h < RW; ++h)
          acc[h][nc] = __builtin_amdgcn_mfma_f32_16x16x32_bf16(a[h], b, acc[h][nc], 0, 0, 0);
      }
      if (more) {
        *reinterpret_cast<uint4*>(&ldsB[cur ^ 1][srow * 40 + skq])        = n0v;
        *reinterpret_cast<uint4*>(&ldsB[cur ^ 1][(64 + srow) * 40 + skq]) = n1v;
        __syncthreads();
        cur ^= 1;
      }
    }
  }

#pragma unroll
  for (int nc = 0; nc < 8; ++nc) {
    const int col = n0 + nc * 16 + r16;
    const float bv = bias ? bias[col] : 0.f;
#pragma unroll
    for (int h = 0; h < RW; ++h) {
#pragma unroll
      for (int r = 0; r < 4; ++r) {
        int m = m0 + wid * (RW * 16) + h * 16 + quad * 4 + r;
        if (m < M) {
          float v = acc[h][nc][r] + bv;
          if (BF16OUT) ((u16*)Cv)[(size_t)m * ldc + col] = f2bf(v);
          else         ((float*)Cv)[(size_t)m * ldc + col] = v;
        }
      }
    }
  }
}

// ---------------------------------------------------------------------------
// Fused GATv2 aggregation (bf16 XLR): one wave per dst node, online softmax
// per head, register accumulation, edges in pairs for ILP.
// XLR row (u16): [xl(0..D-1) | xr(D..2D-1)].
// ---------------------------------------------------------------------------
template<int VPL>
__device__ __forceinline__ void load_row(const u16* p, float* dst) {
  if constexpr (VPL == 8) {
    uint4 t = *reinterpret_cast<const uint4*>(p);
    bf2x2(t.x, dst[0], dst[1]); bf2x2(t.y, dst[2], dst[3]);
    bf2x2(t.z, dst[4], dst[5]); bf2x2(t.w, dst[6], dst[7]);
  } else {
    uint2 t = *reinterpret_cast<const uint2*>(p);
    bf2x2(t.x, dst[0], dst[1]); bf2x2(t.y, dst[2], dst[3]);
  }
}

template<int C>
__global__ __launch_bounds__(256) void gat_node_kernel(
    const u16* __restrict__ XLR,
    const int* __restrict__ rowptr, const int* __restrict__ srcs,
    const float* __restrict__ att, const float* __restrict__ bias,
    u16* __restrict__ Hh, int Nn)
{
  constexpr int D = C * 8;
  constexpr int VPL = D / 64;          // 8 (C=64) or 4 (C=32)
  const int lane = threadIdx.x & 63;
  const int wv  = (blockIdx.x * 256 + threadIdx.x) >> 6;
  const int nwv = (gridDim.x * 256) >> 6;

  float attR[VPL], biasR[VPL];
#pragma unroll
  for (int w = 0; w < VPL; ++w) {
    attR[w]  = att[lane * VPL + w];
    biasR[w] = bias[lane * VPL + w];
  }

  for (int d = wv; d < Nn; d += nwv) {
    float xrR[VPL];
    load_row<VPL>(XLR + (size_t)d * (2 * D) + D + lane * VPL, xrR);

    const int jb = rowptr[d], je = rowptr[d + 1];
    float m = -INFINITY, den = 0.f;
    float acc[VPL];
#pragma unroll
    for (int w = 0; w < VPL; ++w) acc[w] = 0.f;

    int j = jb;
    for (; j + 1 < je; j += 2) {
      float xa[VPL], xb[VPL];
      load_row<VPL>(XLR + (size_t)srcs[j]     * (2 * D) + lane * VPL, xa);
      load_row<VPL>(XLR + (size_t)srcs[j + 1] * (2 * D) + lane * VPL, xb);
      float pa = 0.f, pb = 0.f;
#pragma unroll
      for (int w = 0; w < VPL; ++w) {
        float va = xa[w] + xrR[w]; va = fmaxf(va, 0.2f * va); pa += va * attR[w];
        float vb = xb[w] + xrR[w]; vb = fmaxf(vb, 0.2f * vb); pb += vb * attR[w];
      }
      pa += __shfl_xor(pa, 1); pb += __shfl_xor(pb, 1);
      pa += __shfl_xor(pa, 2); pb += __shfl_xor(pb, 2);
      pa += __shfl_xor(pa, 4); pb += __shfl_xor(pb, 4);
      const float mn = fmaxf(m, fmaxf(pa, pb));
      const float f  = __expf(m - mn);     // m=-inf first iter -> 0
      const float ea = __expf(pa - mn);
      const float eb = __expf(pb - mn);
      den = den * f + ea + eb;
#pragma unroll
      for (int w = 0; w < VPL; ++w)
        acc[w] = acc[w] * f + ea * xa[w] + eb * xb[w];
      m = mn;
    }
    if (j < je) {
      float xa[VPL];
      load_row<VPL>(XLR + (size_t)srcs[j] * (2 * D) + lane * VPL, xa);
      float pa = 0.f;
#pragma unroll
      for (int w = 0; w < VPL; ++w) {
        float va = xa[w] + xrR[w]; va = fmaxf(va, 0.2f * va); pa += va * attR[w];
      }
      pa += __shfl_xor(pa, 1);
      pa += __shfl_xor(pa, 2);
      pa += __shfl_xor(pa, 4);
      const float mn = fmaxf(m, pa);
      const float f  = __expf(m - mn);
      const float ea = __expf(pa - mn);
      den = den * f + ea;
#pragma unroll
      for (int w = 0; w < VPL; ++w) acc[w] = acc[w] * f + ea * xa[w];
      m = mn;
    }

    const float inv = 1.f / den;
    u16* hh = Hh + (size_t)d * D + lane * VPL;
#pragma unroll
    for (int w = 0; w < VPL; ++w) {
      float v = acc[w] * inv + biasR[w];
      v = v > 0.f ? v : expm1f(v);
      hh[w] = f2bf(v);
    }
  }
}

// ---------------------------------------------------------------------------

extern "C" void kernel_launch(void* const* d_in, const int* in_sizes, int n_in,
                              void* d_out, int out_size, void* d_ws, size_t ws_size,
                              hipStream_t stream) {
  const float* x     = (const float*)d_in[0];
  const int*   ei    = (const int*)d_in[1];
  const float* Wl1   = (const float*)d_in[2];
  const float* bl1   = (const float*)d_in[3];
  const float* Wr1   = (const float*)d_in[4];
  const float* br1   = (const float*)d_in[5];
  const float* att1  = (const float*)d_in[6];
  const float* bias1 = (const float*)d_in[7];
  const float* Wl2   = (const float*)d_in[8];
  const float* bl2   = (const float*)d_in[9];
  const float* Wr2   = (const float*)d_in[10];
  const float* br2   = (const float*)d_in[11];
  const float* att2  = (const float*)d_in[12];
  const float* bias2 = (const float*)d_in[13];
  const float* Wjk   = (const float*)d_in[14];
  const float* bjk   = (const float*)d_in[15];
  float* out = (float*)d_out;

  const int Nn = in_sizes[0] / 128;   // 20000
  const int E  = in_sizes[1] / 2;     // 320000
  const int ET = E + Nn;              // 340000

  const size_t nx = (size_t)Nn * 128;   // 2,560,000

  // transposed-weight region offsets (elements)
  const size_t oW1T  = 0;        // [Wl1T|Wr1T] = 1024 rows x 128
  const size_t oW2T  = 131072;   // [Wl2T|Wr2T] = 512 rows x 512
  const size_t oWjkT = 393216;   // WjkT = 128 rows x 896
  const size_t nwsplit = 507904;

  // workspace layout (~80 MB)
  char* ws = (char*)d_ws;
  size_t off = 0;
  u16* XH  = (u16*)(ws + off); off += nx * 2;
  u16* WTH = (u16*)(ws + off); off += nwsplit * 2;
  u16* WTL = (u16*)(ws + off); off += nwsplit * 2;
  float* BC1 = (float*)(ws + off); off += 1024 * 4;
  float* BC2 = (float*)(ws + off); off += 512 * 4;
  u16* XLR1 = (u16*)(ws + off);                 // [N][1024] bf16 (L1)
  u16* XLR2 = XLR1;                             // [N][512]  bf16 (L2, sequential reuse)
  off += (size_t)Nn * 1024 * 2;
  u16* H1h = (u16*)(ws + off); off += (size_t)Nn * 512 * 2;
  u16* H2h = (u16*)(ws + off); off += (size_t)Nn * 256 * 2;
  int* rowptr = (int*)(ws + off); off += (size_t)(Nn + 1) * 4;
  int* cur    = (int*)(ws + off); off += (size_t)Nn * 4;
  int* srcs   = (int*)(ws + off); off += (size_t)ET * 4;

  const int m256 = (Nn + 255) / 256;   // 79  (RW=4 blocks)
  const int m64  = (Nn + 63) / 64;     // 313 (RW=1 blocks)
  const int nodeblocks = 2048;

  // ---------------- prep + CSR build ----------------
  const int nprep = (int)(nx + nwsplit + 1536);
  prep_kernel<<<(nprep + 255) / 256, 256, 0, stream>>>(
      x, Wl1, Wr1, Wl2, Wr2, Wjk, bl1, br1, bl2, br2,
      XH, WTH, WTL, BC1, BC2, (int)nx, nprep);
  hipMemsetAsync(cur, 0, (size_t)Nn * 4, stream);
  hist_kernel<<<(ET + 255) / 256, 256, 0, stream>>>(ei, E, ET, cur);
  scan_kernel<<<1, 1024, 0, stream>>>(cur, rowptr, Nn);
  hipMemsetAsync(cur, 0, (size_t)Nn * 4, stream);
  scatter_kernel<<<(ET + 255) / 256, 256, 0, stream>>>(ei, E, ET, rowptr, cur, srcs);

  // ---------------- Layer 1: XLR1 = XH @ [Wl1|Wr1] (2-term split) ----------
  dim3 g1(m256, 1024 / 128);
  gemm3t_kernel<true, 4><<<g1, 256, 0, stream>>>(
      XH, 128, 128, XH, 128, 128, nullptr, 0, 0,
      WTH + oW1T, WTL + oW1T, nullptr, 128, BC1,
      XLR1, 1024, Nn);
  gat_node_kernel<64><<<nodeblocks, 256, 0, stream>>>(
      XLR1, rowptr, srcs, att1, bias1, H1h, Nn);

  // ---------------- Layer 2: XLR2 = H1h @ [Wl2|Wr2] (2-term split) ---------
  dim3 g2(m256, 512 / 128);
  gemm3t_kernel<true, 4><<<g2, 256, 0, stream>>>(
      H1h, 512, 512, H1h, 512, 512, nullptr, 0, 0,
      WTH + oW2T, WTL + oW2T, nullptr, 512, BC2,
      XLR2, 512, Nn);
  gat_node_kernel<32><<<nodeblocks, 256, 0, stream>>>(
      XLR2, rowptr, srcs, att2, bias2, H2h, Nn);

  // ---------------- JK linear: out = [x|h1|h2] @ Wjk + bjk (hi-only) -------
  dim3 g3(m64, 128 / 128);
  gemm3t_kernel<false, 1><<<g3, 256, 0, stream>>>(
      XH, 128, 128, H1h, 512, 512, H2h, 256, 256,
      WTH + oWjkT, WTH + oWjkT + 128, WTH + oWjkT + 640, 896, bjk,
      out, 128, Nn);
}